// Round 7
// baseline (466.476 us; speedup 1.0000x reference)
//
#include <hip/hip_runtime.h>
#include <math.h>

#define F1 100
#define F2 200

// bucket width 512 nodes
#define BW_LOG 9
#define BW 512

__device__ __forceinline__ float siluf(float v) {
    return v / (1.0f + expf(-v));
}

// batch is sorted: counts via binary-searched boundaries, no atomics.
__global__ void k_batch_bounds(const int* __restrict__ batch, int N, int G,
                               int* __restrict__ starts, int* __restrict__ counts) {
    int t = threadIdx.x;
    if (t <= G) {
        int lo = 0, hi = N;
        while (lo < hi) {
            int mid = (lo + hi) >> 1;
            if (batch[mid] < t) lo = mid + 1; else hi = mid;
        }
        starts[t] = lo;
    }
    __syncthreads();
    if (t < G) counts[t] = starts[t + 1] - starts[t];
}

// ---- bucketed CSR build ----

// A: per-bucket edge histogram (LDS staged, one flush per block).
__global__ __launch_bounds__(256) void k_bucket_count(const int* __restrict__ dst, int E,
                                                      int nbk, int* __restrict__ gcnt) {
    extern __shared__ int cnt[];
    for (int i = threadIdx.x; i < nbk; i += 256) cnt[i] = 0;
    __syncthreads();
    for (int e = blockIdx.x * 256 + threadIdx.x; e < E; e += gridDim.x * 256)
        atomicAdd(&cnt[dst[e] >> BW_LOG], 1);
    __syncthreads();
    for (int i = threadIdx.x; i < nbk; i += 256)
        if (cnt[i]) atomicAdd(&gcnt[i], cnt[i]);
}

// B: exclusive scan of bucket counts -> base; init cursor.
__global__ __launch_bounds__(256) void k_bucket_scan(const int* __restrict__ gcnt, int nbk, int E,
                                                     int* __restrict__ base, int* __restrict__ cursor) {
    __shared__ int sh[256];
    int t = threadIdx.x;
    int v = (t < nbk) ? gcnt[t] : 0;
    sh[t] = v;
    __syncthreads();
    for (int ofs = 1; ofs < 256; ofs <<= 1) {
        int u = (t >= ofs) ? sh[t - ofs] : 0;
        __syncthreads();
        sh[t] += u;
        __syncthreads();
    }
    if (t < nbk) { int ex = sh[t] - v; base[t] = ex; cursor[t] = ex; }
    if (t == 0) base[nbk] = E;
}

// C: scatter (src,dst) pairs into bucket regions with LDS staging (2048 edges/round).
#define CROUND 2048
__global__ __launch_bounds__(256) void k_bucket_scatter(
    const int* __restrict__ src, const int* __restrict__ dst, int E, int nbk,
    int* __restrict__ gcursor, const int* __restrict__ gbase_unused,
    unsigned long long* __restrict__ pairs) {
    __shared__ int cnt[256];
    __shared__ int scanb[256];
    __shared__ int startx[256];
    __shared__ int cur[256];
    __shared__ int gbase[256];
    __shared__ unsigned long long stage[CROUND];
    int tid = threadIdx.x;
    for (long long r0 = (long long)blockIdx.x * CROUND; r0 < E; r0 += (long long)gridDim.x * CROUND) {
        cnt[tid] = 0;
        __syncthreads();
        int ss[8], dd[8], bb[8];
        bool va[8];
        #pragma unroll
        for (int j = 0; j < 8; ++j) {
            long long e = r0 + j * 256 + tid;
            va[j] = (e < E);
            if (va[j]) {
                ss[j] = src[e]; dd[j] = dst[e]; bb[j] = dd[j] >> BW_LOG;
                atomicAdd(&cnt[bb[j]], 1);
            }
        }
        __syncthreads();
        scanb[tid] = cnt[tid];
        __syncthreads();
        for (int ofs = 1; ofs < 256; ofs <<= 1) {
            int u = (tid >= ofs) ? scanb[tid - ofs] : 0;
            __syncthreads();
            scanb[tid] += u;
            __syncthreads();
        }
        int ex = scanb[tid] - cnt[tid];
        startx[tid] = ex;
        cur[tid] = ex;
        if (tid < nbk && cnt[tid] > 0) gbase[tid] = atomicAdd(&gcursor[tid], cnt[tid]);
        __syncthreads();
        int total = scanb[255];
        #pragma unroll
        for (int j = 0; j < 8; ++j) {
            if (va[j]) {
                int slot = atomicAdd(&cur[bb[j]], 1);
                stage[slot] = ((unsigned long long)(unsigned)dd[j] << 32) | (unsigned)ss[j];
            }
        }
        __syncthreads();
        for (int i = tid; i < total; i += 256) {
            unsigned long long p = stage[i];
            int b = (int)(p >> 32) >> BW_LOG;
            pairs[gbase[b] + (i - startx[b])] = p;
        }
        __syncthreads();
    }
}

// D1: per-bucket degree count (LDS) -> deg, dinv.
__global__ __launch_bounds__(512) void k_bucket_deg(
    const unsigned long long* __restrict__ pairs, const int* __restrict__ base,
    int N, int* __restrict__ deg, float* __restrict__ dinv) {
    __shared__ int dl[BW];
    int b = blockIdx.x;
    int t = threadIdx.x;
    dl[t] = 0;
    __syncthreads();
    int beg = base[b], end = base[b + 1];
    for (int i = beg + t; i < end; i += 512) {
        int d = (int)(pairs[i] >> 32);
        atomicAdd(&dl[d & (BW - 1)], 1);
    }
    __syncthreads();
    int node = (b << BW_LOG) + t;
    if (node < N) {
        int dg = dl[t];
        deg[node] = dg;
        dinv[node] = 1.0f / sqrtf((float)dg + 1.0f);
    }
}

// D2: per-bucket CSR fill (LDS cursors, L2-local nbr window) + layer-1 agg in LDS
// + h1 materialization for the bucket's nodes.
__global__ __launch_bounds__(512) void k_bucket_fill_h1(
    const unsigned long long* __restrict__ pairs, const int* __restrict__ base,
    const int* __restrict__ off, const float* __restrict__ x, const float* __restrict__ dinv,
    const float* __restrict__ W1, const float* __restrict__ b1,
    int N, int* __restrict__ nbr, float* __restrict__ h1) {
    __shared__ int offl[BW];
    __shared__ int cur[BW];
    __shared__ float agg[BW];
    int b = blockIdx.x;
    int t = threadIdx.x;
    int node0 = b << BW_LOG;
    int node = node0 + t;
    offl[t] = (node < N) ? off[node] : 0;
    cur[t] = 0;
    agg[t] = 0.0f;
    __syncthreads();
    int beg = base[b], end = base[b + 1];
    for (int i = beg + t; i < end; i += 512) {
        unsigned long long p = pairs[i];
        int s = (int)(p & 0xffffffffu);
        int d = (int)(p >> 32);
        int l = d & (BW - 1);
        int pos = atomicAdd(&cur[l], 1);
        nbr[offl[l] + pos] = s;
        atomicAdd(&agg[l], x[s] * dinv[s]);
    }
    __syncthreads();
    const float2* W1f2 = (const float2*)W1;
    const float2* b1f2 = (const float2*)b1;
    float2* h1f2 = (float2*)h1;
    int lim = BW * (F1 / 2);
    for (int idx = t; idx < lim; idx += 512) {
        int nl = idx / (F1 / 2);
        int pp = idx % (F1 / 2);
        int n = node0 + nl;
        if (n >= N) break;
        float dn = dinv[n];
        float a = dn * (agg[nl] + x[n] * dn);
        float2 w = W1f2[pp];
        float2 bb = b1f2[pp];
        float2 r;
        r.x = siluf(fmaf(a, w.x, bb.x));
        r.y = siluf(fmaf(a, w.y, bb.y));
        h1f2[(size_t)n * (F1 / 2) + pp] = r;
    }
}

// ---- multi-block exclusive scan of deg -> off (3 phases) ----
#define SCHUNK 2048

__global__ __launch_bounds__(256) void k_scan_partial(const int* __restrict__ deg, int N,
                                                      int* __restrict__ partials) {
    __shared__ int red[256];
    int base = blockIdx.x * SCHUNK;
    int s = 0;
    for (int i = threadIdx.x; i < SCHUNK; i += 256) {
        int idx = base + i;
        if (idx < N) s += deg[idx];
    }
    red[threadIdx.x] = s;
    __syncthreads();
    for (int ofs = 128; ofs > 0; ofs >>= 1) {
        if (threadIdx.x < ofs) red[threadIdx.x] += red[threadIdx.x + ofs];
        __syncthreads();
    }
    if (threadIdx.x == 0) partials[blockIdx.x] = red[0];
}

__global__ __launch_bounds__(1024) void k_scan_blocks(int* __restrict__ partials, int nb) {
    __shared__ int sh[1024];
    int t = threadIdx.x;
    int v = (t < nb) ? partials[t] : 0;
    sh[t] = v;
    __syncthreads();
    for (int ofs = 1; ofs < 1024; ofs <<= 1) {
        int u = (t >= ofs) ? sh[t - ofs] : 0;
        __syncthreads();
        sh[t] += u;
        __syncthreads();
    }
    if (t < nb) partials[t] = sh[t] - v;
}

__global__ __launch_bounds__(256) void k_scan_final(const int* __restrict__ deg, int N,
                                                    const int* __restrict__ partials,
                                                    int* __restrict__ off) {
    __shared__ int sh[256];
    int base = blockIdx.x * SCHUNK;
    int i0 = base + threadIdx.x * 8;
    int v[8];
    int s = 0;
    #pragma unroll
    for (int j = 0; j < 8; ++j) {
        int idx = i0 + j;
        v[j] = (idx < N) ? deg[idx] : 0;
        s += v[j];
    }
    int mine = s;
    sh[threadIdx.x] = s;
    __syncthreads();
    for (int ofs = 1; ofs < 256; ofs <<= 1) {
        int u = (threadIdx.x >= ofs) ? sh[threadIdx.x - ofs] : 0;
        __syncthreads();
        sh[threadIdx.x] += u;
        __syncthreads();
    }
    int run = partials[blockIdx.x] + sh[threadIdx.x] - mine;
    #pragma unroll
    for (int j = 0; j < 8; ++j) {
        int idx = i0 + j;
        if (idx < N) { off[idx] = run; run += v[j]; }
    }
    if (N >= i0 && N <= i0 + 8) off[N] = run;
}

// ---- fallback path kernels (ws too small for pairs/h1) ----
__global__ void k_count_deg(const int* __restrict__ dst, int E, int* __restrict__ deg) {
    int i = blockIdx.x * blockDim.x + threadIdx.x;
    if (i < E) atomicAdd(&deg[dst[i]], 1);
}

__global__ void k_dinv_self(const int* __restrict__ deg, const float* __restrict__ x, int N,
                            float* __restrict__ dinv, float* __restrict__ aggx) {
    int i = blockIdx.x * blockDim.x + threadIdx.x;
    if (i < N) {
        float d = 1.0f / sqrtf((float)deg[i] + 1.0f);
        dinv[i] = d;
        aggx[i] = x[i] * d * d;
    }
}

__global__ void k_fill_agg(const int* __restrict__ src, const int* __restrict__ dst, int E,
                           const int* __restrict__ off, int* __restrict__ cursor,
                           int* __restrict__ nbr,
                           const float* __restrict__ x, const float* __restrict__ dinv,
                           float* __restrict__ aggx) {
    int e = blockIdx.x * blockDim.x + threadIdx.x;
    if (e < E) {
        int s = src[e], d = dst[e];
        int p = atomicAdd(&cursor[d], 1);
        nbr[off[d] + p] = s;
        atomicAdd(&aggx[d], x[s] * dinv[s] * dinv[d]);
    }
}

__global__ __launch_bounds__(256) void k_aggh(
    const int* __restrict__ off, const int* __restrict__ nbr,
    const float* __restrict__ aggx, const float* __restrict__ dinv,
    const float* __restrict__ W1, const float* __restrict__ b1,
    int N, float* __restrict__ aggh)
{
    int wave = threadIdx.x >> 6;
    int lane = threadIdx.x & 63;
    int n = blockIdx.x * 4 + wave;
    if (n >= N) return;
    int ja = lane, jb = lane + 64;
    float w1a = (ja < F1) ? W1[ja] : 0.0f;
    float b1a = (ja < F1) ? b1[ja] : 0.0f;
    float w1b = (jb < F1) ? W1[jb] : 0.0f;
    float b1b = (jb < F1) ? b1[jb] : 0.0f;
    float d0 = dinv[n];
    float a0 = aggx[n];
    float accA = siluf(fmaf(a0, w1a, b1a)) * (d0 * d0);
    float accB = siluf(fmaf(a0, w1b, b1b)) * (d0 * d0);
    int beg = off[n], end = off[n + 1];
    for (int t = beg; t < end; t += 64) {
        int cnt = min(64, end - t);
        float sa = 0.0f, sw = 0.0f;
        if (lane < cnt) {
            int s = nbr[t + lane];
            sa = aggx[s];
            sw = dinv[s] * d0;
        }
        for (int i = 0; i < cnt; ++i) {
            float ai = __shfl(sa, i);
            float wi = __shfl(sw, i);
            accA += wi * siluf(fmaf(ai, w1a, b1a));
            accB += wi * siluf(fmaf(ai, w1b, b1b));
        }
    }
    if (ja < F1) aggh[(size_t)n * F1 + ja] = accA;
    if (jb < F1) aggh[(size_t)n * F1 + jb] = accB;
}

// Layer-2 aggregation as a pure gather of materialized h1 rows.
__global__ __launch_bounds__(256) void k_aggh_gather(
    const int* __restrict__ off, const int* __restrict__ nbr,
    const float* __restrict__ h1, const float* __restrict__ dinv,
    int N, float* __restrict__ aggh)
{
    int wave = threadIdx.x >> 6;
    int lane = threadIdx.x & 63;
    int n = blockIdx.x * 4 + wave;
    if (n >= N) return;
    const float2* h1f2 = (const float2*)h1;
    float d0 = dinv[n];
    bool act = lane < (F1 / 2);
    float accx = 0.0f, accy = 0.0f;
    if (act) {
        float2 v = h1f2[(size_t)n * (F1 / 2) + lane];
        accx = v.x * d0 * d0;
        accy = v.y * d0 * d0;
    }
    int beg = off[n], end = off[n + 1];
    for (int t = beg; t < end; t += 64) {
        int cnt = min(64, end - t);
        int sn = 0; float sw = 0.0f;
        if (lane < cnt) {
            sn = nbr[t + lane];
            sw = dinv[sn] * d0;
        }
        int i = 0;
        for (; i + 1 < cnt; i += 2) {
            int   s0 = __shfl(sn, i),     s1 = __shfl(sn, i + 1);
            float w0 = __shfl(sw, i),     w1 = __shfl(sw, i + 1);
            if (act) {
                float2 v0 = h1f2[(size_t)s0 * (F1 / 2) + lane];
                float2 v1 = h1f2[(size_t)s1 * (F1 / 2) + lane];
                accx = fmaf(w0, v0.x, accx); accy = fmaf(w0, v0.y, accy);
                accx = fmaf(w1, v1.x, accx); accy = fmaf(w1, v1.y, accy);
            }
        }
        if (i < cnt) {
            int   s0 = __shfl(sn, i);
            float w0 = __shfl(sw, i);
            if (act) {
                float2 v0 = h1f2[(size_t)s0 * (F1 / 2) + lane];
                accx = fmaf(w0, v0.x, accx); accy = fmaf(w0, v0.y, accy);
            }
        }
    }
    if (act) {
        float2 r; r.x = accx; r.y = accy;
        ((float2*)aggh)[(size_t)n * (F1 / 2) + lane] = r;
    }
}

__global__ void k_h1(const float* __restrict__ aggx, const float* __restrict__ W1,
                     const float* __restrict__ b1, int N, float* __restrict__ h1) {
    int idx = blockIdx.x * blockDim.x + threadIdx.x;
    int total = N * (F1 / 2);
    if (idx >= total) return;
    int n = idx / (F1 / 2);
    int p = idx % (F1 / 2);
    float a = aggx[n];
    float2 w = ((const float2*)W1)[p];
    float2 bb = ((const float2*)b1)[p];
    float2 r;
    r.x = siluf(fmaf(a, w.x, bb.x));
    r.y = siluf(fmaf(a, w.y, bb.y));
    ((float2*)h1)[idx] = r;
}

// Transpose W2 [100][200] -> W2T [200][100] so per-output weight columns are contiguous.
__global__ void k_w2t(const float* __restrict__ W2, float* __restrict__ W2T) {
    int idx = blockIdx.x * blockDim.x + threadIdx.x;
    if (idx < F1 * F2) {
        int m = idx / F1;
        int j = idx % F1;
        W2T[idx] = W2[j * F2 + m];
    }
}

// Fused: h2 = silu(aggh @ W2 + b2), pooled[batch[n]] += h2 (double accumulation).
// v2: weights in 25 float4 REGISTERS per thread (launch_bounds caps prevent scratch
// demotion), activations staged in LDS and read as float4 broadcast (1 LDS instr
// per 4 FMAs), 4 independent accumulators to break the FMA chain.
#define NB2 192
#define NSTG 16
__global__ __launch_bounds__(256, 2) void k_h2_pool2(
    const float* __restrict__ aggh, const float* __restrict__ W2T, const float* __restrict__ b2,
    const int* __restrict__ batch, int N, double* __restrict__ pooled)
{
    __shared__ float sh[NSTG][F1];
    __shared__ int sbatch[NSTG];
    int tid = threadIdx.x;
    int m = tid;
    int base = blockIdx.x * NB2;
    float4 w4[F1 / 4];
    float bb = 0.0f;
    if (m < F2) {
        const float4* wrow = (const float4*)(W2T + (size_t)m * F1);
        #pragma unroll
        for (int q = 0; q < F1 / 4; ++q) w4[q] = wrow[q];
        bb = b2[m];
    }
    double pl = 0.0;
    int gcur = -1;
    for (int t0 = 0; t0 < NB2; t0 += NSTG) {
        __syncthreads();
        for (int idx = tid; idx < NSTG * (F1 / 4); idx += 256) {
            int r = idx / (F1 / 4), q = idx % (F1 / 4);
            int n = base + t0 + r;
            float4 v = make_float4(0.f, 0.f, 0.f, 0.f);
            if (n < N) v = ((const float4*)(aggh + (size_t)n * F1))[q];
            ((float4*)&sh[r][0])[q] = v;
        }
        if (tid < NSTG) {
            int n = base + t0 + tid;
            sbatch[tid] = (n < N) ? batch[n] : -1;
        }
        __syncthreads();
        if (m < F2) {
            for (int r = 0; r < NSTG; ++r) {
                int n = base + t0 + r;
                if (n >= N) break;
                int g = sbatch[r];
                if (g != gcur) {
                    if (gcur >= 0) atomicAdd(&pooled[(size_t)gcur * F2 + m], pl);
                    pl = 0.0;
                    gcur = g;
                }
                const float4* a4 = (const float4*)&sh[r][0];
                float ac0 = 0.f, ac1 = 0.f, ac2 = 0.f, ac3 = 0.f;
                #pragma unroll
                for (int q = 0; q < F1 / 4; ++q) {
                    float4 a = a4[q];
                    ac0 = fmaf(a.x, w4[q].x, ac0);
                    ac1 = fmaf(a.y, w4[q].y, ac1);
                    ac2 = fmaf(a.z, w4[q].z, ac2);
                    ac3 = fmaf(a.w, w4[q].w, ac3);
                }
                float acc = ((ac0 + ac1) + (ac2 + ac3)) + bb;
                pl += (double)siluf(acc);
            }
        }
    }
    if (gcur >= 0 && m < F2) atomicAdd(&pooled[(size_t)gcur * F2 + m], pl);
}

// Head MLP: one block per graph, double precision.
__global__ __launch_bounds__(256) void k_head(
    const double* __restrict__ pooled, const int* __restrict__ counts,
    const float* __restrict__ Wl1, const float* __restrict__ bl1,
    const float* __restrict__ Wl2, const float* __restrict__ bl2,
    float* __restrict__ out)
{
    int g = blockIdx.x;
    int tid = threadIdx.x;
    __shared__ double sp[F2];
    __shared__ double red[256];
    double icnt = 1.0 / (double)max(counts[g], 1);
    for (int m = tid; m < F2; m += 256) sp[m] = pooled[(size_t)g * F2 + m] * icnt;
    __syncthreads();
    double part = 0.0;
    if (tid < 100) {
        double acc = (double)bl1[tid];
        #pragma unroll 4
        for (int m = 0; m < F2; ++m) acc += sp[m] * (double)Wl1[m * 100 + tid];
        double t1 = acc / (1.0 + exp(-acc));
        part = t1 * (double)Wl2[tid];
    }
    red[tid] = part;
    __syncthreads();
    for (int s = 128; s > 0; s >>= 1) {
        if (tid < s) red[tid] += red[tid + s];
        __syncthreads();
    }
    if (tid == 0) out[g] = (float)(red[0] + (double)bl2[0]);
}

extern "C" void kernel_launch(void* const* d_in, const int* in_sizes, int n_in,
                              void* d_out, int out_size, void* d_ws, size_t ws_size,
                              hipStream_t stream)
{
    const float* x   = (const float*)d_in[0];
    const int*   src = (const int*)d_in[1];
    const int*   dst = (const int*)d_in[2];
    const int*   batch = (const int*)d_in[3];
    const float* W1  = (const float*)d_in[4];
    const float* b1  = (const float*)d_in[5];
    const float* W2  = (const float*)d_in[6];
    const float* b2  = (const float*)d_in[7];
    const float* Wl1 = (const float*)d_in[8];
    const float* bl1 = (const float*)d_in[9];
    const float* Wl2 = (const float*)d_in[10];
    const float* bl2 = (const float*)d_in[11];
    int N = in_sizes[0];
    int E = in_sizes[1];
    int G = out_size;
    float* out = (float*)d_out;

    char* ws = (char*)d_ws;
    size_t o = 0;
    auto alloc = [&](size_t bytes) -> void* {
        o = (o + 255) & ~(size_t)255;
        void* p = ws + o;
        o += bytes;
        return p;
    };
    int nscan = (N + SCHUNK - 1) / SCHUNK;
    int nbk = (N + BW - 1) / BW;
    int*    deg    = (int*)alloc((size_t)N * 4);
    int*    cursor = (int*)alloc((size_t)N * 4);
    int*    off    = (int*)alloc((size_t)(N + 1) * 4);
    int*    nbr    = (int*)alloc((size_t)E * 4);
    float*  dinv   = (float*)alloc((size_t)N * 4);
    float*  aggx   = (float*)alloc((size_t)N * 4);
    float*  aggh   = (float*)alloc((size_t)N * F1 * 4);
    double* pooled = (double*)alloc((size_t)G * F2 * 8);
    int*    counts = (int*)alloc((size_t)G * 4);
    int*    starts = (int*)alloc((size_t)(G + 1) * 4);
    int*    partials = (int*)alloc((size_t)nscan * 4);
    int*    bcnt   = (int*)alloc((size_t)nbk * 4);
    int*    bbase  = (int*)alloc((size_t)(nbk + 1) * 4);
    int*    bcur   = (int*)alloc((size_t)nbk * 4);
    float*  W2T    = (float*)alloc((size_t)F1 * F2 * 4);
    // gated large buffers
    o = (o + 255) & ~(size_t)255;
    float* h1 = (float*)(ws + o);
    bool use_h1 = (o + (size_t)N * F1 * 4) <= ws_size;
    size_t o2 = o + (use_h1 ? (size_t)N * F1 * 4 : 0);
    o2 = (o2 + 255) & ~(size_t)255;
    unsigned long long* pairs = (unsigned long long*)(ws + o2);
    bool use_bucket = use_h1 && ((o2 + (size_t)E * 8) <= ws_size);

    hipMemsetAsync(pooled, 0, (size_t)G * F2 * 8, stream);

    int tE = (E + 255) / 256;
    int tN = (N + 255) / 256;
    k_batch_bounds<<<1, 128, 0, stream>>>(batch, N, G, starts, counts);
    k_w2t<<<(F1 * F2 + 255) / 256, 256, 0, stream>>>(W2, W2T);

    if (use_bucket) {
        hipMemsetAsync(bcnt, 0, (size_t)nbk * 4, stream);
        k_bucket_count<<<240, 256, nbk * 4, stream>>>(dst, E, nbk, bcnt);
        k_bucket_scan<<<1, 256, 0, stream>>>(bcnt, nbk, E, bbase, bcur);
        k_bucket_scatter<<<240, 256, 0, stream>>>(src, dst, E, nbk, bcur, bbase, pairs);
        k_bucket_deg<<<nbk, 512, 0, stream>>>(pairs, bbase, N, deg, dinv);
        k_scan_partial<<<nscan, 256, 0, stream>>>(deg, N, partials);
        k_scan_blocks<<<1, 1024, 0, stream>>>(partials, nscan);
        k_scan_final<<<nscan, 256, 0, stream>>>(deg, N, partials, off);
        k_bucket_fill_h1<<<nbk, 512, 0, stream>>>(pairs, bbase, off, x, dinv, W1, b1, N, nbr, h1);
        k_aggh_gather<<<(N + 3) / 4, 256, 0, stream>>>(off, nbr, h1, dinv, N, aggh);
    } else {
        hipMemsetAsync(deg, 0, (size_t)N * 4, stream);
        hipMemsetAsync(cursor, 0, (size_t)N * 4, stream);
        k_count_deg<<<tE, 256, 0, stream>>>(dst, E, deg);
        k_dinv_self<<<tN, 256, 0, stream>>>(deg, x, N, dinv, aggx);
        k_scan_partial<<<nscan, 256, 0, stream>>>(deg, N, partials);
        k_scan_blocks<<<1, 1024, 0, stream>>>(partials, nscan);
        k_scan_final<<<nscan, 256, 0, stream>>>(deg, N, partials, off);
        k_fill_agg<<<tE, 256, 0, stream>>>(src, dst, E, off, cursor, nbr, x, dinv, aggx);
        if (use_h1) {
            int th1 = (N * (F1 / 2) + 255) / 256;
            k_h1<<<th1, 256, 0, stream>>>(aggx, W1, b1, N, h1);
            k_aggh_gather<<<(N + 3) / 4, 256, 0, stream>>>(off, nbr, h1, dinv, N, aggh);
        } else {
            k_aggh<<<(N + 3) / 4, 256, 0, stream>>>(off, nbr, aggx, dinv, W1, b1, N, aggh);
        }
    }
    k_h2_pool2<<<(N + NB2 - 1) / NB2, 256, 0, stream>>>(aggh, W2T, b2, batch, N, pooled);
    k_head<<<G, 256, 0, stream>>>(pooled, counts, Wl1, bl1, Wl2, bl2, out);
}

// Round 8
// 336.801 us; speedup vs baseline: 1.3850x; 1.3850x over previous
//
#include <hip/hip_runtime.h>
#include <math.h>

#define F1 100
#define F2 200

// bucket width 512 nodes
#define BW_LOG 9
#define BW 512

__device__ __forceinline__ float siluf(float v) {
    return v / (1.0f + expf(-v));
}

// batch is sorted: counts via binary-searched boundaries, no atomics.
__global__ void k_batch_bounds(const int* __restrict__ batch, int N, int G,
                               int* __restrict__ starts, int* __restrict__ counts) {
    int t = threadIdx.x;
    if (t <= G) {
        int lo = 0, hi = N;
        while (lo < hi) {
            int mid = (lo + hi) >> 1;
            if (batch[mid] < t) lo = mid + 1; else hi = mid;
        }
        starts[t] = lo;
    }
    __syncthreads();
    if (t < G) counts[t] = starts[t + 1] - starts[t];
}

// ---- bucketed CSR build ----

__global__ __launch_bounds__(256) void k_bucket_count(const int* __restrict__ dst, int E,
                                                      int nbk, int* __restrict__ gcnt) {
    extern __shared__ int cnt[];
    for (int i = threadIdx.x; i < nbk; i += 256) cnt[i] = 0;
    __syncthreads();
    for (int e = blockIdx.x * 256 + threadIdx.x; e < E; e += gridDim.x * 256)
        atomicAdd(&cnt[dst[e] >> BW_LOG], 1);
    __syncthreads();
    for (int i = threadIdx.x; i < nbk; i += 256)
        if (cnt[i]) atomicAdd(&gcnt[i], cnt[i]);
}

__global__ __launch_bounds__(256) void k_bucket_scan(const int* __restrict__ gcnt, int nbk, int E,
                                                     int* __restrict__ base, int* __restrict__ cursor) {
    __shared__ int sh[256];
    int t = threadIdx.x;
    int v = (t < nbk) ? gcnt[t] : 0;
    sh[t] = v;
    __syncthreads();
    for (int ofs = 1; ofs < 256; ofs <<= 1) {
        int u = (t >= ofs) ? sh[t - ofs] : 0;
        __syncthreads();
        sh[t] += u;
        __syncthreads();
    }
    if (t < nbk) { int ex = sh[t] - v; base[t] = ex; cursor[t] = ex; }
    if (t == 0) base[nbk] = E;
}

#define CROUND 2048
__global__ __launch_bounds__(256) void k_bucket_scatter(
    const int* __restrict__ src, const int* __restrict__ dst, int E, int nbk,
    int* __restrict__ gcursor, const int* __restrict__ gbase_unused,
    unsigned long long* __restrict__ pairs) {
    __shared__ int cnt[256];
    __shared__ int scanb[256];
    __shared__ int startx[256];
    __shared__ int cur[256];
    __shared__ int gbase[256];
    __shared__ unsigned long long stage[CROUND];
    int tid = threadIdx.x;
    for (long long r0 = (long long)blockIdx.x * CROUND; r0 < E; r0 += (long long)gridDim.x * CROUND) {
        cnt[tid] = 0;
        __syncthreads();
        int ss[8], dd[8], bb[8];
        bool va[8];
        #pragma unroll
        for (int j = 0; j < 8; ++j) {
            long long e = r0 + j * 256 + tid;
            va[j] = (e < E);
            if (va[j]) {
                ss[j] = src[e]; dd[j] = dst[e]; bb[j] = dd[j] >> BW_LOG;
                atomicAdd(&cnt[bb[j]], 1);
            }
        }
        __syncthreads();
        scanb[tid] = cnt[tid];
        __syncthreads();
        for (int ofs = 1; ofs < 256; ofs <<= 1) {
            int u = (tid >= ofs) ? scanb[tid - ofs] : 0;
            __syncthreads();
            scanb[tid] += u;
            __syncthreads();
        }
        int ex = scanb[tid] - cnt[tid];
        startx[tid] = ex;
        cur[tid] = ex;
        if (tid < nbk && cnt[tid] > 0) gbase[tid] = atomicAdd(&gcursor[tid], cnt[tid]);
        __syncthreads();
        int total = scanb[255];
        #pragma unroll
        for (int j = 0; j < 8; ++j) {
            if (va[j]) {
                int slot = atomicAdd(&cur[bb[j]], 1);
                stage[slot] = ((unsigned long long)(unsigned)dd[j] << 32) | (unsigned)ss[j];
            }
        }
        __syncthreads();
        for (int i = tid; i < total; i += 256) {
            unsigned long long p = stage[i];
            int b = (int)(p >> 32) >> BW_LOG;
            pairs[gbase[b] + (i - startx[b])] = p;
        }
        __syncthreads();
    }
}

__global__ __launch_bounds__(512) void k_bucket_deg(
    const unsigned long long* __restrict__ pairs, const int* __restrict__ base,
    int N, int* __restrict__ deg, float* __restrict__ dinv) {
    __shared__ int dl[BW];
    int b = blockIdx.x;
    int t = threadIdx.x;
    dl[t] = 0;
    __syncthreads();
    int beg = base[b], end = base[b + 1];
    for (int i = beg + t; i < end; i += 512) {
        int d = (int)(pairs[i] >> 32);
        atomicAdd(&dl[d & (BW - 1)], 1);
    }
    __syncthreads();
    int node = (b << BW_LOG) + t;
    if (node < N) {
        int dg = dl[t];
        deg[node] = dg;
        dinv[node] = 1.0f / sqrtf((float)dg + 1.0f);
    }
}

__global__ __launch_bounds__(512) void k_bucket_fill_h1(
    const unsigned long long* __restrict__ pairs, const int* __restrict__ base,
    const int* __restrict__ off, const float* __restrict__ x, const float* __restrict__ dinv,
    const float* __restrict__ W1, const float* __restrict__ b1,
    int N, int* __restrict__ nbr, float* __restrict__ h1) {
    __shared__ int offl[BW];
    __shared__ int cur[BW];
    __shared__ float agg[BW];
    int b = blockIdx.x;
    int t = threadIdx.x;
    int node0 = b << BW_LOG;
    int node = node0 + t;
    offl[t] = (node < N) ? off[node] : 0;
    cur[t] = 0;
    agg[t] = 0.0f;
    __syncthreads();
    int beg = base[b], end = base[b + 1];
    for (int i = beg + t; i < end; i += 512) {
        unsigned long long p = pairs[i];
        int s = (int)(p & 0xffffffffu);
        int d = (int)(p >> 32);
        int l = d & (BW - 1);
        int pos = atomicAdd(&cur[l], 1);
        nbr[offl[l] + pos] = s;
        atomicAdd(&agg[l], x[s] * dinv[s]);
    }
    __syncthreads();
    const float2* W1f2 = (const float2*)W1;
    const float2* b1f2 = (const float2*)b1;
    float2* h1f2 = (float2*)h1;
    int lim = BW * (F1 / 2);
    for (int idx = t; idx < lim; idx += 512) {
        int nl = idx / (F1 / 2);
        int pp = idx % (F1 / 2);
        int n = node0 + nl;
        if (n >= N) break;
        float dn = dinv[n];
        float a = dn * (agg[nl] + x[n] * dn);
        float2 w = W1f2[pp];
        float2 bb = b1f2[pp];
        float2 r;
        r.x = siluf(fmaf(a, w.x, bb.x));
        r.y = siluf(fmaf(a, w.y, bb.y));
        h1f2[(size_t)n * (F1 / 2) + pp] = r;
    }
}

// ---- multi-block exclusive scan of deg -> off (3 phases) ----
#define SCHUNK 2048

__global__ __launch_bounds__(256) void k_scan_partial(const int* __restrict__ deg, int N,
                                                      int* __restrict__ partials) {
    __shared__ int red[256];
    int base = blockIdx.x * SCHUNK;
    int s = 0;
    for (int i = threadIdx.x; i < SCHUNK; i += 256) {
        int idx = base + i;
        if (idx < N) s += deg[idx];
    }
    red[threadIdx.x] = s;
    __syncthreads();
    for (int ofs = 128; ofs > 0; ofs >>= 1) {
        if (threadIdx.x < ofs) red[threadIdx.x] += red[threadIdx.x + ofs];
        __syncthreads();
    }
    if (threadIdx.x == 0) partials[blockIdx.x] = red[0];
}

__global__ __launch_bounds__(1024) void k_scan_blocks(int* __restrict__ partials, int nb) {
    __shared__ int sh[1024];
    int t = threadIdx.x;
    int v = (t < nb) ? partials[t] : 0;
    sh[t] = v;
    __syncthreads();
    for (int ofs = 1; ofs < 1024; ofs <<= 1) {
        int u = (t >= ofs) ? sh[t - ofs] : 0;
        __syncthreads();
        sh[t] += u;
        __syncthreads();
    }
    if (t < nb) partials[t] = sh[t] - v;
}

__global__ __launch_bounds__(256) void k_scan_final(const int* __restrict__ deg, int N,
                                                    const int* __restrict__ partials,
                                                    int* __restrict__ off) {
    __shared__ int sh[256];
    int base = blockIdx.x * SCHUNK;
    int i0 = base + threadIdx.x * 8;
    int v[8];
    int s = 0;
    #pragma unroll
    for (int j = 0; j < 8; ++j) {
        int idx = i0 + j;
        v[j] = (idx < N) ? deg[idx] : 0;
        s += v[j];
    }
    int mine = s;
    sh[threadIdx.x] = s;
    __syncthreads();
    for (int ofs = 1; ofs < 256; ofs <<= 1) {
        int u = (threadIdx.x >= ofs) ? sh[threadIdx.x - ofs] : 0;
        __syncthreads();
        sh[threadIdx.x] += u;
        __syncthreads();
    }
    int run = partials[blockIdx.x] + sh[threadIdx.x] - mine;
    #pragma unroll
    for (int j = 0; j < 8; ++j) {
        int idx = i0 + j;
        if (idx < N) { off[idx] = run; run += v[j]; }
    }
    if (N >= i0 && N <= i0 + 8) off[N] = run;
}

// ---- fallback path kernels (ws too small for pairs/h1) ----
__global__ void k_count_deg(const int* __restrict__ dst, int E, int* __restrict__ deg) {
    int i = blockIdx.x * blockDim.x + threadIdx.x;
    if (i < E) atomicAdd(&deg[dst[i]], 1);
}

__global__ void k_dinv_self(const int* __restrict__ deg, const float* __restrict__ x, int N,
                            float* __restrict__ dinv, float* __restrict__ aggx) {
    int i = blockIdx.x * blockDim.x + threadIdx.x;
    if (i < N) {
        float d = 1.0f / sqrtf((float)deg[i] + 1.0f);
        dinv[i] = d;
        aggx[i] = x[i] * d * d;
    }
}

__global__ void k_fill_agg(const int* __restrict__ src, const int* __restrict__ dst, int E,
                           const int* __restrict__ off, int* __restrict__ cursor,
                           int* __restrict__ nbr,
                           const float* __restrict__ x, const float* __restrict__ dinv,
                           float* __restrict__ aggx) {
    int e = blockIdx.x * blockDim.x + threadIdx.x;
    if (e < E) {
        int s = src[e], d = dst[e];
        int p = atomicAdd(&cursor[d], 1);
        nbr[off[d] + p] = s;
        atomicAdd(&aggx[d], x[s] * dinv[s] * dinv[d]);
    }
}

__global__ __launch_bounds__(256) void k_aggh(
    const int* __restrict__ off, const int* __restrict__ nbr,
    const float* __restrict__ aggx, const float* __restrict__ dinv,
    const float* __restrict__ W1, const float* __restrict__ b1,
    int N, float* __restrict__ aggh)
{
    int wave = threadIdx.x >> 6;
    int lane = threadIdx.x & 63;
    int n = blockIdx.x * 4 + wave;
    if (n >= N) return;
    int ja = lane, jb = lane + 64;
    float w1a = (ja < F1) ? W1[ja] : 0.0f;
    float b1a = (ja < F1) ? b1[ja] : 0.0f;
    float w1b = (jb < F1) ? W1[jb] : 0.0f;
    float b1b = (jb < F1) ? b1[jb] : 0.0f;
    float d0 = dinv[n];
    float a0 = aggx[n];
    float accA = siluf(fmaf(a0, w1a, b1a)) * (d0 * d0);
    float accB = siluf(fmaf(a0, w1b, b1b)) * (d0 * d0);
    int beg = off[n], end = off[n + 1];
    for (int t = beg; t < end; t += 64) {
        int cnt = min(64, end - t);
        float sa = 0.0f, sw = 0.0f;
        if (lane < cnt) {
            int s = nbr[t + lane];
            sa = aggx[s];
            sw = dinv[s] * d0;
        }
        for (int i = 0; i < cnt; ++i) {
            float ai = __shfl(sa, i);
            float wi = __shfl(sw, i);
            accA += wi * siluf(fmaf(ai, w1a, b1a));
            accB += wi * siluf(fmaf(ai, w1b, b1b));
        }
    }
    if (ja < F1) aggh[(size_t)n * F1 + ja] = accA;
    if (jb < F1) aggh[(size_t)n * F1 + jb] = accB;
}

// Layer-2 aggregation as a pure gather of materialized h1 rows.
__global__ __launch_bounds__(256) void k_aggh_gather(
    const int* __restrict__ off, const int* __restrict__ nbr,
    const float* __restrict__ h1, const float* __restrict__ dinv,
    int N, float* __restrict__ aggh)
{
    int wave = threadIdx.x >> 6;
    int lane = threadIdx.x & 63;
    int n = blockIdx.x * 4 + wave;
    if (n >= N) return;
    const float2* h1f2 = (const float2*)h1;
    float d0 = dinv[n];
    bool act = lane < (F1 / 2);
    float accx = 0.0f, accy = 0.0f;
    if (act) {
        float2 v = h1f2[(size_t)n * (F1 / 2) + lane];
        accx = v.x * d0 * d0;
        accy = v.y * d0 * d0;
    }
    int beg = off[n], end = off[n + 1];
    for (int t = beg; t < end; t += 64) {
        int cnt = min(64, end - t);
        int sn = 0; float sw = 0.0f;
        if (lane < cnt) {
            sn = nbr[t + lane];
            sw = dinv[sn] * d0;
        }
        int i = 0;
        for (; i + 1 < cnt; i += 2) {
            int   s0 = __shfl(sn, i),     s1 = __shfl(sn, i + 1);
            float w0 = __shfl(sw, i),     w1 = __shfl(sw, i + 1);
            if (act) {
                float2 v0 = h1f2[(size_t)s0 * (F1 / 2) + lane];
                float2 v1 = h1f2[(size_t)s1 * (F1 / 2) + lane];
                accx = fmaf(w0, v0.x, accx); accy = fmaf(w0, v0.y, accy);
                accx = fmaf(w1, v1.x, accx); accy = fmaf(w1, v1.y, accy);
            }
        }
        if (i < cnt) {
            int   s0 = __shfl(sn, i);
            float w0 = __shfl(sw, i);
            if (act) {
                float2 v0 = h1f2[(size_t)s0 * (F1 / 2) + lane];
                accx = fmaf(w0, v0.x, accx); accy = fmaf(w0, v0.y, accy);
            }
        }
    }
    if (act) {
        float2 r; r.x = accx; r.y = accy;
        ((float2*)aggh)[(size_t)n * (F1 / 2) + lane] = r;
    }
}

__global__ void k_h1(const float* __restrict__ aggx, const float* __restrict__ W1,
                     const float* __restrict__ b1, int N, float* __restrict__ h1) {
    int idx = blockIdx.x * blockDim.x + threadIdx.x;
    int total = N * (F1 / 2);
    if (idx >= total) return;
    int n = idx / (F1 / 2);
    int p = idx % (F1 / 2);
    float a = aggx[n];
    float2 w = ((const float2*)W1)[p];
    float2 bb = ((const float2*)b1)[p];
    float2 r;
    r.x = siluf(fmaf(a, w.x, bb.x));
    r.y = siluf(fmaf(a, w.y, bb.y));
    ((float2*)h1)[idx] = r;
}

// Fused h2 = silu(aggh @ W2 + b2) + graph pooling, register-microtiled GEMM.
// Block: 20 nodes x 200 feats. Thread: 4 nodes x 4 feats (16 acc, ~40 live VGPRs).
// Weights shared via LDS (k-major tiles of W2, no transpose needed).
// sA padded to 101 so the 5 node-groups hit distinct banks.
#define HP_NODES 20
#define HP_KT 25
__global__ __launch_bounds__(256) void k_h2_pool3(
    const float* __restrict__ aggh, const float* __restrict__ W2, const float* __restrict__ b2,
    const int* __restrict__ batch, int N, double* __restrict__ pooled)
{
    __shared__ float smem[HP_KT * F2 + HP_NODES * (F1 + 1)];  // sW(5000) + sA(2020)
    float* sW = smem;                    // [HP_KT][F2], aliased by sOut later
    float* sA = smem + HP_KT * F2;       // [HP_NODES][F1+1]
    float* sOut = smem;                  // [HP_NODES][F2] = 4000 <= 5000
    __shared__ int sbatch[HP_NODES];

    int tid = threadIdx.x;
    int base = blockIdx.x * HP_NODES;

    // stage activations (padded rows) and batch ids
    for (int idx = tid; idx < HP_NODES * (F1 / 4); idx += 256) {
        int i = idx / (F1 / 4), q = idx % (F1 / 4);
        int n = base + i;
        float4 v = make_float4(0.f, 0.f, 0.f, 0.f);
        if (n < N) v = *(const float4*)(aggh + (size_t)n * F1 + q * 4);
        float* dp = &sA[i * (F1 + 1) + q * 4];
        dp[0] = v.x; dp[1] = v.y; dp[2] = v.z; dp[3] = v.w;
    }
    if (tid < HP_NODES) {
        int n = base + tid;
        sbatch[tid] = (n < N) ? batch[n] : -1;
    }

    const int fgrp = tid % 50;
    const int ngrp = tid / 50;      // 0..4 active (tid<250)
    const int m0 = fgrp * 4;
    const int i0 = ngrp * 4;
    const bool act = (tid < 250);

    float acc[4][4];
    #pragma unroll
    for (int i = 0; i < 4; ++i)
        #pragma unroll
        for (int j = 0; j < 4; ++j) acc[i][j] = 0.0f;

    for (int kt = 0; kt < F1; kt += HP_KT) {
        __syncthreads();   // sA ready (1st iter) / prev compute done
        for (int idx = tid; idx < (HP_KT * F2) / 4; idx += 256)
            ((float4*)sW)[idx] = ((const float4*)(W2 + (size_t)kt * F2))[idx];
        __syncthreads();
        if (act) {
            #pragma unroll
            for (int kk = 0; kk < HP_KT; ++kk) {
                float4 w = *(const float4*)&sW[kk * F2 + m0];
                int k = kt + kk;
                float a0 = sA[(i0 + 0) * (F1 + 1) + k];
                float a1 = sA[(i0 + 1) * (F1 + 1) + k];
                float a2 = sA[(i0 + 2) * (F1 + 1) + k];
                float a3 = sA[(i0 + 3) * (F1 + 1) + k];
                acc[0][0] = fmaf(a0, w.x, acc[0][0]); acc[0][1] = fmaf(a0, w.y, acc[0][1]);
                acc[0][2] = fmaf(a0, w.z, acc[0][2]); acc[0][3] = fmaf(a0, w.w, acc[0][3]);
                acc[1][0] = fmaf(a1, w.x, acc[1][0]); acc[1][1] = fmaf(a1, w.y, acc[1][1]);
                acc[1][2] = fmaf(a1, w.z, acc[1][2]); acc[1][3] = fmaf(a1, w.w, acc[1][3]);
                acc[2][0] = fmaf(a2, w.x, acc[2][0]); acc[2][1] = fmaf(a2, w.y, acc[2][1]);
                acc[2][2] = fmaf(a2, w.z, acc[2][2]); acc[2][3] = fmaf(a2, w.w, acc[2][3]);
                acc[3][0] = fmaf(a3, w.x, acc[3][0]); acc[3][1] = fmaf(a3, w.y, acc[3][1]);
                acc[3][2] = fmaf(a3, w.z, acc[3][2]); acc[3][3] = fmaf(a3, w.w, acc[3][3]);
            }
        }
    }
    __syncthreads();   // all reads of sW done before aliasing as sOut
    if (act) {
        float4 bb = *(const float4*)(b2 + m0);
        #pragma unroll
        for (int i = 0; i < 4; ++i) {
            float4 r;
            r.x = siluf(acc[i][0] + bb.x);
            r.y = siluf(acc[i][1] + bb.y);
            r.z = siluf(acc[i][2] + bb.z);
            r.w = siluf(acc[i][3] + bb.w);
            *(float4*)&sOut[(i0 + i) * F2 + m0] = r;
        }
    }
    __syncthreads();
    if (tid < F2) {
        double pl = 0.0;
        int gcur = -1;
        for (int i = 0; i < HP_NODES; ++i) {
            int n = base + i;
            if (n >= N) break;
            int g = sbatch[i];
            if (g != gcur) {
                if (gcur >= 0) atomicAdd(&pooled[(size_t)gcur * F2 + tid], pl);
                pl = 0.0;
                gcur = g;
            }
            pl += (double)sOut[i * F2 + tid];
        }
        if (gcur >= 0) atomicAdd(&pooled[(size_t)gcur * F2 + tid], pl);
    }
}

// Head MLP: one block per graph, double precision.
__global__ __launch_bounds__(256) void k_head(
    const double* __restrict__ pooled, const int* __restrict__ counts,
    const float* __restrict__ Wl1, const float* __restrict__ bl1,
    const float* __restrict__ Wl2, const float* __restrict__ bl2,
    float* __restrict__ out)
{
    int g = blockIdx.x;
    int tid = threadIdx.x;
    __shared__ double sp[F2];
    __shared__ double red[256];
    double icnt = 1.0 / (double)max(counts[g], 1);
    for (int m = tid; m < F2; m += 256) sp[m] = pooled[(size_t)g * F2 + m] * icnt;
    __syncthreads();
    double part = 0.0;
    if (tid < 100) {
        double acc = (double)bl1[tid];
        #pragma unroll 4
        for (int m = 0; m < F2; ++m) acc += sp[m] * (double)Wl1[m * 100 + tid];
        double t1 = acc / (1.0 + exp(-acc));
        part = t1 * (double)Wl2[tid];
    }
    red[tid] = part;
    __syncthreads();
    for (int s = 128; s > 0; s >>= 1) {
        if (tid < s) red[tid] += red[tid + s];
        __syncthreads();
    }
    if (tid == 0) out[g] = (float)(red[0] + (double)bl2[0]);
}

extern "C" void kernel_launch(void* const* d_in, const int* in_sizes, int n_in,
                              void* d_out, int out_size, void* d_ws, size_t ws_size,
                              hipStream_t stream)
{
    const float* x   = (const float*)d_in[0];
    const int*   src = (const int*)d_in[1];
    const int*   dst = (const int*)d_in[2];
    const int*   batch = (const int*)d_in[3];
    const float* W1  = (const float*)d_in[4];
    const float* b1  = (const float*)d_in[5];
    const float* W2  = (const float*)d_in[6];
    const float* b2  = (const float*)d_in[7];
    const float* Wl1 = (const float*)d_in[8];
    const float* bl1 = (const float*)d_in[9];
    const float* Wl2 = (const float*)d_in[10];
    const float* bl2 = (const float*)d_in[11];
    int N = in_sizes[0];
    int E = in_sizes[1];
    int G = out_size;
    float* out = (float*)d_out;

    char* ws = (char*)d_ws;
    size_t o = 0;
    auto alloc = [&](size_t bytes) -> void* {
        o = (o + 255) & ~(size_t)255;
        void* p = ws + o;
        o += bytes;
        return p;
    };
    int nscan = (N + SCHUNK - 1) / SCHUNK;
    int nbk = (N + BW - 1) / BW;
    int*    deg    = (int*)alloc((size_t)N * 4);
    int*    cursor = (int*)alloc((size_t)N * 4);
    int*    off    = (int*)alloc((size_t)(N + 1) * 4);
    int*    nbr    = (int*)alloc((size_t)E * 4);
    float*  dinv   = (float*)alloc((size_t)N * 4);
    float*  aggx   = (float*)alloc((size_t)N * 4);
    float*  aggh   = (float*)alloc((size_t)N * F1 * 4);
    double* pooled = (double*)alloc((size_t)G * F2 * 8);
    int*    counts = (int*)alloc((size_t)G * 4);
    int*    starts = (int*)alloc((size_t)(G + 1) * 4);
    int*    partials = (int*)alloc((size_t)nscan * 4);
    int*    bcnt   = (int*)alloc((size_t)nbk * 4);
    int*    bbase  = (int*)alloc((size_t)(nbk + 1) * 4);
    int*    bcur   = (int*)alloc((size_t)nbk * 4);
    // gated large buffers
    o = (o + 255) & ~(size_t)255;
    float* h1 = (float*)(ws + o);
    bool use_h1 = (o + (size_t)N * F1 * 4) <= ws_size;
    size_t o2 = o + (use_h1 ? (size_t)N * F1 * 4 : 0);
    o2 = (o2 + 255) & ~(size_t)255;
    unsigned long long* pairs = (unsigned long long*)(ws + o2);
    bool use_bucket = use_h1 && ((o2 + (size_t)E * 8) <= ws_size);

    hipMemsetAsync(pooled, 0, (size_t)G * F2 * 8, stream);

    int tE = (E + 255) / 256;
    int tN = (N + 255) / 256;
    k_batch_bounds<<<1, 128, 0, stream>>>(batch, N, G, starts, counts);

    if (use_bucket) {
        hipMemsetAsync(bcnt, 0, (size_t)nbk * 4, stream);
        k_bucket_count<<<240, 256, nbk * 4, stream>>>(dst, E, nbk, bcnt);
        k_bucket_scan<<<1, 256, 0, stream>>>(bcnt, nbk, E, bbase, bcur);
        k_bucket_scatter<<<240, 256, 0, stream>>>(src, dst, E, nbk, bcur, bbase, pairs);
        k_bucket_deg<<<nbk, 512, 0, stream>>>(pairs, bbase, N, deg, dinv);
        k_scan_partial<<<nscan, 256, 0, stream>>>(deg, N, partials);
        k_scan_blocks<<<1, 1024, 0, stream>>>(partials, nscan);
        k_scan_final<<<nscan, 256, 0, stream>>>(deg, N, partials, off);
        k_bucket_fill_h1<<<nbk, 512, 0, stream>>>(pairs, bbase, off, x, dinv, W1, b1, N, nbr, h1);
        k_aggh_gather<<<(N + 3) / 4, 256, 0, stream>>>(off, nbr, h1, dinv, N, aggh);
    } else {
        hipMemsetAsync(deg, 0, (size_t)N * 4, stream);
        hipMemsetAsync(cursor, 0, (size_t)N * 4, stream);
        k_count_deg<<<tE, 256, 0, stream>>>(dst, E, deg);
        k_dinv_self<<<tN, 256, 0, stream>>>(deg, x, N, dinv, aggx);
        k_scan_partial<<<nscan, 256, 0, stream>>>(deg, N, partials);
        k_scan_blocks<<<1, 1024, 0, stream>>>(partials, nscan);
        k_scan_final<<<nscan, 256, 0, stream>>>(deg, N, partials, off);
        k_fill_agg<<<tE, 256, 0, stream>>>(src, dst, E, off, cursor, nbr, x, dinv, aggx);
        if (use_h1) {
            int th1 = (N * (F1 / 2) + 255) / 256;
            k_h1<<<th1, 256, 0, stream>>>(aggx, W1, b1, N, h1);
            k_aggh_gather<<<(N + 3) / 4, 256, 0, stream>>>(off, nbr, h1, dinv, N, aggh);
        } else {
            k_aggh<<<(N + 3) / 4, 256, 0, stream>>>(off, nbr, aggx, dinv, W1, b1, N, aggh);
        }
    }
    k_h2_pool3<<<(N + HP_NODES - 1) / HP_NODES, 256, 0, stream>>>(aggh, W2, b2, batch, N, pooled);
    k_head<<<G, 256, 0, stream>>>(pooled, counts, Wl1, bl1, Wl2, bl2, out);
}